// Round 10
// baseline (582.137 us; speedup 1.0000x reference)
//
#include <hip/hip_runtime.h>
#include <hip/hip_bf16.h>

using bf16x8  = __attribute__((ext_vector_type(8))) short;
using f32x2   = __attribute__((ext_vector_type(2))) float;
using f32x4   = __attribute__((ext_vector_type(4))) float;
using ushort8 = __attribute__((ext_vector_type(8))) unsigned short;

#define BB   32
#define CIN  128
#define COUT 128
#define PODS 2
#define HIN  56
#define WIN  56
#define HW   4096   // 64*64 padded spatial, natural [kh][kw] flat index
#define GRID 1024
#define TPB  256

__device__ __forceinline__ unsigned short bf16bits(float v) {
  __hip_bfloat16 h = __float2bfloat16(v);
  return reinterpret_cast<unsigned short&>(h);
}
__device__ __forceinline__ float bits2f(unsigned short u) {
  return __uint_as_float(((unsigned)u) << 16);
}

// 64-pt FWHT on 32 x f32x2 (value w lives at a[w>>1][w&1]).
__device__ __forceinline__ void fwht64v(f32x2 (&a)[32]) {
  #pragma unroll
  for (int i = 0; i < 32; ++i) {
    float u = a[i][0], v = a[i][1];
    a[i][0] = u + v; a[i][1] = u - v;
  }
  #pragma unroll
  for (int d = 1; d <= 16; d <<= 1) {
    #pragma unroll
    for (int i = 0; i < 32; i += 2*d) {
      #pragma unroll
      for (int j = 0; j < d; ++j) {
        f32x2 u = a[i+j], v = a[i+j+d];
        a[i+j]   = u + v;
        a[i+j+d] = u - v;
      }
    }
  }
}

#define LDS_WAIT() asm volatile("s_waitcnt lgkmcnt(0)" ::: "memory")

// Manual grid barrier. Arrival: one device-scope fetch_add per block.
// Poll: device-scope atomic LOAD (no RMW -> no ownership serialization)
// with s_sleep backoff. Fence structure identical to the R9-proven one.
__device__ __forceinline__ void grid_barrier(unsigned* cnt, unsigned target) {
  __threadfence();
  __syncthreads();
  if (threadIdx.x == 0) {
    __hip_atomic_fetch_add(cnt, 1u, __ATOMIC_RELAXED, __HIP_MEMORY_SCOPE_AGENT);
    while (__hip_atomic_load(cnt, __ATOMIC_RELAXED, __HIP_MEMORY_SCOPE_AGENT) < target) {
      __builtin_amdgcn_s_sleep(32);
    }
  }
  __syncthreads();
  __threadfence();
}

// ---- phase 1 body: forward 2D FWHT of tile bc (wave-local, 9216B LDS region)
__device__ __forceinline__ void fwd_tile(const float* __restrict__ x,
                                         unsigned short* __restrict__ F,
                                         char* sm, int bc, int lane) {
  f32x2 av[32];
  #pragma unroll
  for (int i = 0; i < 32; ++i) av[i] = (f32x2){0.f, 0.f};
  if (lane < WIN) {
    const float* xp = x + (size_t)bc*(HIN*WIN) + lane;
    #pragma unroll
    for (int h = 0; h < HIN; ++h) av[h>>1][h&1] = xp[h*WIN];
  }

  fwht64v(av);                                 // over h (lane owns w=lane)

  #pragma unroll
  for (int k = 0; k < 64; ++k)
    *reinterpret_cast<unsigned short*>(&sm[k*144 + lane*2]) = bf16bits(av[k>>1][k&1]);
  LDS_WAIT();
  #pragma unroll
  for (int c = 0; c < 8; ++c) {
    ushort8 v = *reinterpret_cast<const ushort8*>(&sm[lane*144 + c*16]);
    #pragma unroll
    for (int e = 0; e < 8; ++e) av[c*4 + (e>>1)][e&1] = bits2f(v[e]);
  }
  LDS_WAIT();

  fwht64v(av);                                 // over w (lane owns kh=lane)

  #pragma unroll
  for (int j = 0; j < 8; ++j) {
    ushort8 v;
    #pragma unroll
    for (int e = 0; e < 8; ++e) v[e] = bf16bits(av[j*4 + (e>>1)][e&1]);
    *reinterpret_cast<ushort8*>(&sm[lane*144 + j*16]) = v;
  }
  LDS_WAIT();

  unsigned short* Fp = F + (size_t)bc * HW;
  #pragma unroll
  for (int jj = 0; jj < 8; ++jj) {
    int r = jj*8 + (lane >> 3);
    ushort8 v = *reinterpret_cast<const ushort8*>(&sm[r*144 + (lane & 7)*16]);
    *reinterpret_cast<ushort8*>(Fp + jj*512 + lane*8) = v;
  }
}

// ---- phase 3 body: inverse 2D FWHT of tile bo: y = crop(IWHT(G+F))/4096
__device__ __forceinline__ void inv_tile(const unsigned short* __restrict__ G,
                                         const unsigned short* __restrict__ F,
                                         float* __restrict__ y,
                                         char* sm, int bo, int lane) {
  const unsigned short* Gp = G + (size_t)bo * HW;
  const unsigned short* Fp = F + (size_t)bo * HW;
  #pragma unroll
  for (int jj = 0; jj < 8; ++jj) {
    ushort8 g = *reinterpret_cast<const ushort8*>(Gp + jj*512 + lane*8);
    ushort8 f = *reinterpret_cast<const ushort8*>(Fp + jj*512 + lane*8);
    int kh = jj*8 + (lane >> 3);
    ushort8 s;
    #pragma unroll
    for (int e = 0; e < 8; ++e) s[e] = bf16bits(bits2f(g[e]) + bits2f(f[e]));
    *reinterpret_cast<ushort8*>(&sm[kh*144 + (lane & 7)*16]) = s;
  }
  LDS_WAIT();

  f32x2 av[32];
  #pragma unroll
  for (int k = 0; k < 64; ++k)
    av[k>>1][k&1] = bits2f(*reinterpret_cast<const unsigned short*>(&sm[k*144 + lane*2]));
  LDS_WAIT();

  fwht64v(av);                                 // over kh

  #pragma unroll
  for (int h = 0; h < 64; ++h)
    *reinterpret_cast<unsigned short*>(&sm[h*144 + lane*2]) = bf16bits(av[h>>1][h&1]);
  LDS_WAIT();
  #pragma unroll
  for (int c = 0; c < 8; ++c) {
    ushort8 v = *reinterpret_cast<const ushort8*>(&sm[lane*144 + c*16]);
    #pragma unroll
    for (int e = 0; e < 8; ++e) av[c*4 + (e>>1)][e&1] = bits2f(v[e]);
  }
  LDS_WAIT();

  fwht64v(av);                                 // over kw -> y row h=lane

  #pragma unroll
  for (int i = 0; i < 32; ++i) av[i] *= (1.f/4096.f);

  float (*tf)[72] = reinterpret_cast<float(*)[72]>(sm);
  float* yp = y + (size_t)bo*(HIN*WIN) + lane;

  if (lane < 32) {
    #pragma unroll
    for (int w4 = 0; w4 < 16; ++w4) {
      float4 v = {av[w4*2][0], av[w4*2][1], av[w4*2+1][0], av[w4*2+1][1]};
      *reinterpret_cast<float4*>(&tf[lane][w4*4]) = v;
    }
  }
  LDS_WAIT();
  if (lane < WIN) {
    #pragma unroll
    for (int h = 0; h < 32; ++h) yp[h*WIN] = tf[h][lane];
  }
  LDS_WAIT();
  if (lane >= 32 && lane < HIN) {
    #pragma unroll
    for (int w4 = 0; w4 < 16; ++w4) {
      float4 v = {av[w4*2][0], av[w4*2][1], av[w4*2+1][0], av[w4*2+1][1]};
      *reinterpret_cast<float4*>(&tf[lane - 32][w4*4]) = v;
    }
  }
  LDS_WAIT();
  if (lane < WIN) {
    #pragma unroll
    for (int h = 32; h < HIN; ++h) yp[h*WIN] = tf[h - 32][lane];
  }
}

// ---- fused persistent kernel: fwd (1 tile/wave) | gridbar | mix (1 unit/blk)
//      | gridbar | ifwht (1 tile/wave).  1024 blocks, 4 blocks/CU resident.
__global__ __launch_bounds__(TPB, 4) void k_fused(const float* __restrict__ x,
                                                  const float* __restrict__ cw,
                                                  const float* __restrict__ lv,
                                                  const float* __restrict__ T,
                                                  unsigned short* __restrict__ F,
                                                  unsigned short* __restrict__ G,
                                                  float* __restrict__ y,
                                                  unsigned* __restrict__ bar) {
  __shared__ __align__(16) char smem[4*9216];   // 36864 B; phase2 uses 33792 B
  const int tid  = threadIdx.x;
  const int wv   = tid >> 6;
  const int lane = tid & 63;
  const int blk  = blockIdx.x;

  // ================= phase 1: forward FWHT (4096 tiles, 1/wave) ============
  {
    char* sm = smem + wv*9216;
    fwd_tile(x, F, sm, blk*4 + wv, lane);
  }
  grid_barrier(bar, GRID);

  // ================= phase 2: mix (1024 units, 1/block) ====================
  {
    char* FT = smem;                                    // 32768 B
    float (*ev)[128] = reinterpret_cast<float(*)[128]>(smem + 32768);

    const int b    = blk >> 5;
    const int hwb  = blk & 31;

    // A fragments (conv_w) + thresholds
    bf16x8 afr[PODS][2][4];
    {
      const int g8 = (lane >> 4) * 8;
      #pragma unroll
      for (int p = 0; p < PODS; ++p)
        #pragma unroll
        for (int tm = 0; tm < 2; ++tm)
          #pragma unroll
          for (int kk = 0; kk < 4; ++kk) {
            int o = wv*32 + tm*16 + (lane & 15);
            const float* wp = cw + ((size_t)(p*COUT + o))*CIN + kk*32 + g8;
            float4 w0 = *reinterpret_cast<const float4*>(wp);
            float4 w1 = *reinterpret_cast<const float4*>(wp + 4);
            bf16x8 fr;
            fr[0] = (short)bf16bits(w0.x); fr[1] = (short)bf16bits(w0.y);
            fr[2] = (short)bf16bits(w0.z); fr[3] = (short)bf16bits(w0.w);
            fr[4] = (short)bf16bits(w1.x); fr[5] = (short)bf16bits(w1.y);
            fr[6] = (short)bf16bits(w1.z); fr[7] = (short)bf16bits(w1.w);
            afr[p][tm][kk] = fr;
          }
    }
    float th[2][4];
    #pragma unroll
    for (int tm = 0; tm < 2; ++tm)
      #pragma unroll
      for (int r = 0; r < 4; ++r)
        th[tm][r] = fmaxf(T[wv*32 + tm*16 + (lane >> 4)*4 + r], 0.f);

    { // ev table
      int p = tid >> 7, h = tid & 127;
      ev[p][h] = expf(lv[p*HW + hwb*128 + h]);
    }
    { // stage FT: lane owns hw rows {2l,2l+1}, wave owns i-range wv*32..+31
      const unsigned short* Fb = F + (size_t)b*CIN*HW + hwb*128 + 2*lane;
      const int i0w = wv*32;
      unsigned uu[32];
      #pragma unroll
      for (int i = 0; i < 32; ++i)
        uu[i] = *reinterpret_cast<const unsigned*>(Fb + (size_t)(i0w + i)*HW);
      const int r0 = 2*lane, r1 = 2*lane + 1;
      #pragma unroll
      for (int m = 0; m < 4; ++m) {
        ushort8 v0, v1;
        #pragma unroll
        for (int e = 0; e < 8; ++e) {
          unsigned u = uu[m*8 + e];
          v0[e] = (unsigned short)(u & 0xffffu);
          v1[e] = (unsigned short)(u >> 16);
        }
        int colb = wv*64 + m*16;
        *reinterpret_cast<ushort8*>(&FT[r0*256 + (colb ^ ((r0&15)<<4))]) = v0;
        *reinterpret_cast<ushort8*>(&FT[r1*256 + (colb ^ ((r1&15)<<4))]) = v1;
      }
    }
    __syncthreads();

    unsigned short* Gb = G + (size_t)b * COUT * HW + hwb*128;
    #pragma unroll
    for (int t = 0; t < 8; ++t) {
      f32x4 acc[2][2];  // [tm][pod]
      #pragma unroll
      for (int tm = 0; tm < 2; ++tm)
        #pragma unroll
        for (int p = 0; p < PODS; ++p)
          acc[tm][p] = (f32x4){0.f, 0.f, 0.f, 0.f};

      const int row = t*16 + (lane & 15);
      const int rb  = row << 8;
      const int sw  = (row & 15) << 4;
      #pragma unroll
      for (int kk = 0; kk < 4; ++kk) {
        int cb = (kk*64 + (lane >> 4)*16) ^ sw;
        bf16x8 bfrag = *reinterpret_cast<const bf16x8*>(&FT[rb + cb]);
        #pragma unroll
        for (int tm = 0; tm < 2; ++tm) {
          acc[tm][0] = __builtin_amdgcn_mfma_f32_16x16x32_bf16(afr[0][tm][kk], bfrag, acc[tm][0], 0, 0, 0);
          acc[tm][1] = __builtin_amdgcn_mfma_f32_16x16x32_bf16(afr[1][tm][kk], bfrag, acc[tm][1], 0, 0, 0);
        }
      }

      const float v0 = ev[0][t*16 + (lane & 15)];
      const float v1 = ev[1][t*16 + (lane & 15)];
      #pragma unroll
      for (int tm = 0; tm < 2; ++tm) {
        #pragma unroll
        for (int r = 0; r < 4; ++r) {
          float f = v0*acc[tm][0][r] + v1*acc[tm][1][r];
          float m = fabsf(f) - th[tm][r];
          m = m > 0.f ? m : 0.f;
          int o = wv*32 + tm*16 + (lane >> 4)*4 + r;
          Gb[(size_t)o*HW + t*16 + (lane & 15)] = bf16bits(copysignf(m, f));
        }
      }
    }
  }
  grid_barrier(bar, 2*GRID);

  // ================= phase 3: inverse FWHT (4096 tiles, 1/wave) ============
  {
    char* sm = smem + wv*9216;
    inv_tile(G, F, y, sm, blk*4 + wv, lane);
  }
}

extern "C" void kernel_launch(void* const* d_in, const int* in_sizes, int n_in,
                              void* d_out, int out_size, void* d_ws, size_t ws_size,
                              hipStream_t stream) {
  const float* x  = (const float*)d_in[0];
  const float* cw = (const float*)d_in[1];
  const float* lv = (const float*)d_in[2];
  const float* T  = (const float*)d_in[3];
  float* y = (float*)d_out;

  char* ws = (char*)d_ws;
  const size_t szF = (size_t)BB * CIN * HW * 2;   // 33.5 MB
  const size_t szG = (size_t)BB * COUT * HW * 2;  // 33.5 MB

  unsigned short* F   = (unsigned short*)ws;
  unsigned short* G   = (unsigned short*)(ws + szF);
  unsigned*       bar = (unsigned*)(ws + szF + szG);
  (void)ws_size;

  // zero the barrier counter every call (deterministic across graph replays)
  hipMemsetAsync(bar, 0, sizeof(unsigned), stream);

  k_fused<<<dim3(GRID), dim3(TPB), 0, stream>>>(x, cw, lv, T, F, G, y, bar);
}

// Round 11
// 69.965 us; speedup vs baseline: 8.3204x; 8.3204x over previous
//
#include <hip/hip_runtime.h>
#include <hip/hip_bf16.h>

using bf16x8  = __attribute__((ext_vector_type(8))) short;
using f32x2   = __attribute__((ext_vector_type(2))) float;
using f32x4   = __attribute__((ext_vector_type(4))) float;
using ushort8 = __attribute__((ext_vector_type(8))) unsigned short;

#define BB   32
#define CIN  128
#define COUT 128
#define PODS 2
#define HIN  56
#define WIN  56
#define HW   4096   // 64*64 padded spatial, natural [kh][kw] flat index

__device__ __forceinline__ unsigned short bf16bits(float v) {
  __hip_bfloat16 h = __float2bfloat16(v);
  return reinterpret_cast<unsigned short&>(h);
}
__device__ __forceinline__ float bits2f(unsigned short u) {
  return __uint_as_float(((unsigned)u) << 16);
}

// 64-pt FWHT on 32 x f32x2 (value w lives at a[w>>1][w&1]).
// Stage 1 is intra-vector; stages 2..32 are whole-vector ops -> v_pk_add_f32.
__device__ __forceinline__ void fwht64v(f32x2 (&a)[32]) {
  #pragma unroll
  for (int i = 0; i < 32; ++i) {
    float u = a[i][0], v = a[i][1];
    a[i][0] = u + v; a[i][1] = u - v;
  }
  #pragma unroll
  for (int d = 1; d <= 16; d <<= 1) {
    #pragma unroll
    for (int i = 0; i < 32; i += 2*d) {
      #pragma unroll
      for (int j = 0; j < d; ++j) {
        f32x2 u = a[i+j], v = a[i+j+d];
        a[i+j]   = u + v;
        a[i+j+d] = u - v;
      }
    }
  }
}

#define LDS_WAIT() asm volatile("s_waitcnt lgkmcnt(0)" ::: "memory")

// ---- forward 2D FWHT per (b,c); pad 56x56 -> 64x64; write bf16 F[b][c][kh][kw] ----
// Single wave; 9.2KB bf16 LDS tile [64 rows][72 shorts] (144B stride).
__global__ __launch_bounds__(64, 4) void k_fwht_fwd(const float* __restrict__ x,
                                                    unsigned short* __restrict__ F) {
  const int bc   = blockIdx.x;
  const int lane = threadIdx.x;

  __shared__ __align__(16) char smem[64*144];

  // coalesced x load: lane = w column; 56 instrs x 224B contiguous
  f32x2 av[32];
  #pragma unroll
  for (int i = 0; i < 32; ++i) av[i] = (f32x2){0.f, 0.f};
  if (lane < WIN) {
    const float* xp = x + (size_t)bc*(HIN*WIN) + lane;
    #pragma unroll
    for (int h = 0; h < HIN; ++h) av[h>>1][h&1] = xp[h*WIN];
  }

  fwht64v(av);                                 // transform over h (lane owns w=lane)

  // transpose via bf16 tile: write column lane (2B, 2 lanes/bank = free)
  #pragma unroll
  for (int k = 0; k < 64; ++k)
    *reinterpret_cast<unsigned short*>(&smem[k*144 + lane*2]) = bf16bits(av[k>>1][k&1]);
  LDS_WAIT();
  // read row lane: 8 x b128 (144B stride -> minimal 8-lane/slot pattern)
  #pragma unroll
  for (int c = 0; c < 8; ++c) {
    ushort8 v = *reinterpret_cast<const ushort8*>(&smem[lane*144 + c*16]);
    #pragma unroll
    for (int e = 0; e < 8; ++e) av[c*4 + (e>>1)][e&1] = bits2f(v[e]);
  }
  LDS_WAIT();

  fwht64v(av);                                 // transform over w (lane owns kh=lane)

  // staging: write row kh=lane as bf16 chunks (same tile)
  #pragma unroll
  for (int j = 0; j < 8; ++j) {
    ushort8 v;
    #pragma unroll
    for (int e = 0; e < 8; ++e) v[e] = bf16bits(av[j*4 + (e>>1)][e&1]);
    *reinterpret_cast<ushort8*>(&smem[lane*144 + j*16]) = v;
  }
  LDS_WAIT();

  // coalesced F store: 8 instrs x 1KB contiguous
  unsigned short* Fp = F + (size_t)bc * HW;
  #pragma unroll
  for (int jj = 0; jj < 8; ++jj) {
    int r = jj*8 + (lane >> 3);
    ushort8 v = *reinterpret_cast<const ushort8*>(&smem[r*144 + (lane & 7)*16]);
    *reinterpret_cast<ushort8*>(Fp + jj*512 + lane*8) = v;
  }
}

// ---- mixing: f6[b,o,hw] = softthr( sum_p v_p(hw) * sum_i W[p,o,i]*F[b,i,hw] ) ----
// v-scale commuted out of the GEMM: B-tile = raw F bf16, shared across pods;
// v applied in the f32 epilogue. B-frags via swizzled ds_read_b128 on an LDS
// [hw 128][i 128] tile (XOR mask (row&15)<<4).
__global__ __launch_bounds__(256, 3) void k_mix(const unsigned short* F,
                                                const float* __restrict__ cw,
                                                const float* __restrict__ lv,
                                                const float* __restrict__ T,
                                                unsigned short* G) {
  const int wg   = blockIdx.x;
  const int swz  = (wg & 7)*128 + (wg >> 3);
  const int b    = swz >> 5;
  const int hwb  = swz & 31;            // hw0 = hwb*128
  const int tid  = threadIdx.x;
  const int wv   = tid >> 6;
  const int l    = tid & 63;

  __shared__ __align__(16) char FT[32768];   // [hw 128][i 128] bf16, XOR-swizzled rows
  __shared__ float ev[PODS][128];

  {
    int p = tid >> 7, h = tid & 127;
    ev[p][h] = expf(lv[p*HW + hwb*128 + h]);
  }

  {
    const unsigned short* Fb = F + (size_t)b*CIN*HW + hwb*128 + 2*l;
    const int i0w = wv*32;
    unsigned uu[32];
    #pragma unroll
    for (int i = 0; i < 32; ++i)
      uu[i] = *reinterpret_cast<const unsigned*>(Fb + (size_t)(i0w + i)*HW);
    const int r0 = 2*l, r1 = 2*l + 1;
    #pragma unroll
    for (int m = 0; m < 4; ++m) {
      ushort8 v0, v1;
      #pragma unroll
      for (int e = 0; e < 8; ++e) {
        unsigned u = uu[m*8 + e];
        v0[e] = (unsigned short)(u & 0xffffu);
        v1[e] = (unsigned short)(u >> 16);
      }
      int colb = wv*64 + m*16;
      *reinterpret_cast<ushort8*>(&FT[r0*256 + (colb ^ ((r0&15)<<4))]) = v0;
      *reinterpret_cast<ushort8*>(&FT[r1*256 + (colb ^ ((r1&15)<<4))]) = v1;
    }
  }

  bf16x8 afr[PODS][2][4];
  {
    const int g8 = (l >> 4) * 8;
    #pragma unroll
    for (int p = 0; p < PODS; ++p)
      #pragma unroll
      for (int tm = 0; tm < 2; ++tm)
        #pragma unroll
        for (int kk = 0; kk < 4; ++kk) {
          int o = wv*32 + tm*16 + (l & 15);
          const float* wp = cw + ((size_t)(p*COUT + o))*CIN + kk*32 + g8;
          float4 w0 = *reinterpret_cast<const float4*>(wp);
          float4 w1 = *reinterpret_cast<const float4*>(wp + 4);
          bf16x8 fr;
          fr[0] = (short)bf16bits(w0.x); fr[1] = (short)bf16bits(w0.y);
          fr[2] = (short)bf16bits(w0.z); fr[3] = (short)bf16bits(w0.w);
          fr[4] = (short)bf16bits(w1.x); fr[5] = (short)bf16bits(w1.y);
          fr[6] = (short)bf16bits(w1.z); fr[7] = (short)bf16bits(w1.w);
          afr[p][tm][kk] = fr;
        }
  }

  float th[2][4];
  #pragma unroll
  for (int tm = 0; tm < 2; ++tm)
    #pragma unroll
    for (int r = 0; r < 4; ++r)
      th[tm][r] = fmaxf(T[wv*32 + tm*16 + (l >> 4)*4 + r], 0.f);

  __syncthreads();

  unsigned short* Gb = G + (size_t)b * COUT * HW + hwb*128;

  #pragma unroll
  for (int t = 0; t < 8; ++t) {
    f32x4 acc[2][2];  // [tm][pod]
    #pragma unroll
    for (int tm = 0; tm < 2; ++tm)
      #pragma unroll
      for (int p = 0; p < PODS; ++p)
        acc[tm][p] = (f32x4){0.f, 0.f, 0.f, 0.f};

    const int row = t*16 + (l & 15);
    const int rb  = row << 8;
    const int sw  = (row & 15) << 4;
    #pragma unroll
    for (int kk = 0; kk < 4; ++kk) {
      int cb = (kk*64 + (l >> 4)*16) ^ sw;
      bf16x8 bfrag = *reinterpret_cast<const bf16x8*>(&FT[rb + cb]);
      #pragma unroll
      for (int tm = 0; tm < 2; ++tm) {
        acc[tm][0] = __builtin_amdgcn_mfma_f32_16x16x32_bf16(afr[0][tm][kk], bfrag, acc[tm][0], 0, 0, 0);
        acc[tm][1] = __builtin_amdgcn_mfma_f32_16x16x32_bf16(afr[1][tm][kk], bfrag, acc[tm][1], 0, 0, 0);
      }
    }

    const float v0 = ev[0][t*16 + (l & 15)];
    const float v1 = ev[1][t*16 + (l & 15)];
    #pragma unroll
    for (int tm = 0; tm < 2; ++tm) {
      #pragma unroll
      for (int r = 0; r < 4; ++r) {
        float f = v0*acc[tm][0][r] + v1*acc[tm][1][r];
        float m = fabsf(f) - th[tm][r];
        m = m > 0.f ? m : 0.f;
        int o = wv*32 + tm*16 + (l >> 4)*4 + r;
        Gb[(size_t)o*HW + t*16 + (l & 15)] = bf16bits(copysignf(m, f));
      }
    }
  }
}

// ---- inverse 2D FWHT per (b,o): y = crop(IWHT(G + F))/4096 ----
// bf16 9.2KB tile for deposit/transpose; f32 two-phase writeback for y.
__global__ __launch_bounds__(64, 4) void k_ifwht(const unsigned short* __restrict__ G,
                                                 const unsigned short* __restrict__ F,
                                                 float* __restrict__ y) {
  const int bo   = blockIdx.x;
  const int lane = threadIdx.x;

  __shared__ __align__(16) char smem[64*144];

  // deposit G+F rows -> bf16 tile [kh][kw] (144B stride)
  const unsigned short* Gp = G + (size_t)bo * HW;
  const unsigned short* Fp = F + (size_t)bo * HW;
  #pragma unroll
  for (int jj = 0; jj < 8; ++jj) {
    ushort8 g = *reinterpret_cast<const ushort8*>(Gp + jj*512 + lane*8);
    ushort8 f = *reinterpret_cast<const ushort8*>(Fp + jj*512 + lane*8);
    int kh = jj*8 + (lane >> 3);
    ushort8 s;
    #pragma unroll
    for (int e = 0; e < 8; ++e) s[e] = bf16bits(bits2f(g[e]) + bits2f(f[e]));
    *reinterpret_cast<ushort8*>(&smem[kh*144 + (lane & 7)*16]) = s;
  }
  LDS_WAIT();

  // column read: lane owns kw=lane
  f32x2 av[32];
  #pragma unroll
  for (int k = 0; k < 64; ++k)
    av[k>>1][k&1] = bits2f(*reinterpret_cast<const unsigned short*>(&smem[k*144 + lane*2]));
  LDS_WAIT();

  fwht64v(av);                                 // over kh

  // transpose: write column lane, read row lane
  #pragma unroll
  for (int h = 0; h < 64; ++h)
    *reinterpret_cast<unsigned short*>(&smem[h*144 + lane*2]) = bf16bits(av[h>>1][h&1]);
  LDS_WAIT();
  #pragma unroll
  for (int c = 0; c < 8; ++c) {
    ushort8 v = *reinterpret_cast<const ushort8*>(&smem[lane*144 + c*16]);
    #pragma unroll
    for (int e = 0; e < 8; ++e) av[c*4 + (e>>1)][e&1] = bits2f(v[e]);
  }
  LDS_WAIT();

  fwht64v(av);                                 // over kw -> y row h=lane, w contiguous

  // scale 1/4096
  #pragma unroll
  for (int i = 0; i < 32; ++i) av[i] *= (1.f/4096.f);

  // f32 two-phase writeback + coalesced y store (tile as f32[32][72], 288B stride)
  float (*tf)[72] = reinterpret_cast<float(*)[72]>(smem);
  float* yp = y + (size_t)bo*(HIN*WIN) + lane;

  if (lane < 32) {
    #pragma unroll
    for (int w4 = 0; w4 < 16; ++w4) {
      float4 v = {av[w4*2][0], av[w4*2][1], av[w4*2+1][0], av[w4*2+1][1]};
      *reinterpret_cast<float4*>(&tf[lane][w4*4]) = v;
    }
  }
  LDS_WAIT();
  if (lane < WIN) {
    #pragma unroll
    for (int h = 0; h < 32; ++h) yp[h*WIN] = tf[h][lane];
  }
  LDS_WAIT();
  if (lane >= 32 && lane < HIN) {
    #pragma unroll
    for (int w4 = 0; w4 < 16; ++w4) {
      float4 v = {av[w4*2][0], av[w4*2][1], av[w4*2+1][0], av[w4*2+1][1]};
      *reinterpret_cast<float4*>(&tf[lane - 32][w4*4]) = v;
    }
  }
  LDS_WAIT();
  if (lane < WIN) {
    #pragma unroll
    for (int h = 32; h < HIN; ++h) yp[h*WIN] = tf[h - 32][lane];
  }
}

extern "C" void kernel_launch(void* const* d_in, const int* in_sizes, int n_in,
                              void* d_out, int out_size, void* d_ws, size_t ws_size,
                              hipStream_t stream) {
  const float* x  = (const float*)d_in[0];
  const float* cw = (const float*)d_in[1];
  const float* lv = (const float*)d_in[2];
  const float* T  = (const float*)d_in[3];
  float* y = (float*)d_out;

  char* ws = (char*)d_ws;
  const size_t szF = (size_t)BB * CIN * HW * 2;   // 33.5 MB

  unsigned short* F  = (unsigned short*)ws;
  unsigned short* G  = (unsigned short*)(ws + szF);
  (void)ws_size;

  k_fwht_fwd<<<dim3(BB*CIN),  dim3(64),  0, stream>>>(x, F);
  k_mix     <<<dim3(BB*32),   dim3(256), 0, stream>>>(F, cw, lv, T, G);
  k_ifwht   <<<dim3(BB*COUT), dim3(64),  0, stream>>>(G, F, y);
}